// Round 11
// baseline (21.127 us; speedup 1.0000x reference)
//
#include <hip/hip_runtime.h>
#include <math.h>

namespace {
constexpr int L = 512, S = 512, H = 8, D = 64, K64 = 64;
constexpr float LOG2E = 1.4426950408889634f;
constexpr int PADS = 266;            // f32 plane stride: even (8B align) + <=2-way banks
constexpr int NOFF = 16 * PADS;      // D-plane offset inside planes[]

typedef __bf16 bf16x8 __attribute__((ext_vector_type(8)));
typedef float  f32x4  __attribute__((ext_vector_type(4)));

// ws layout: Ap only — [32 mtA][16 ks][4 kg][16 r] bf16x8 = 512 KiB @ 0
//   A[l][k]: l = mtA*16+r, k = ks*32+kg*8+e; A = bf16(u@v^T + mask)

__device__ inline f32x4 mfma16(bf16x8 a, bf16x8 b, f32x4 c) {
    return __builtin_amdgcn_mfma_f32_16x16x32_bf16(a, b, c, 0, 0, 0);
}

// K1: A-prep. 128 blocks x 256 threads. Thread (r,kg) computes one bf16x8
// fragment unit (8 s-dots of K=64) with broadcast v-loads; one fully
// coalesced 1KB wave-store per wave.
__global__ __launch_bounds__(256) void aft_a_kernel(
    const float* __restrict__ u, const float* __restrict__ v,
    const float* __restrict__ mask, __bf16* __restrict__ Ap)
{
    const int bid = blockIdx.x;          // 0..127
    const int t = threadIdx.x;
    const int mtA = bid >> 2;
    const int scq = bid & 3;
    const int wv = t >> 6;
    const int lane = t & 63;
    const int r = lane & 15;
    const int kg = lane >> 4;
    const int ks = scq * 4 + wv;
    const int l = mtA * 16 + r;
    const int sb = ks * 32 + kg * 8;

    float acc[8] = {};
    const float* urow = u + (size_t)l * K64;
    #pragma unroll
    for (int c = 0; c < K64; c += 4) {
        const float4 u4 = *reinterpret_cast<const float4*>(urow + c);
        #pragma unroll
        for (int e = 0; e < 8; ++e) {
            const float4 v4 =
                *reinterpret_cast<const float4*>(v + (size_t)(sb + e) * K64 + c);
            acc[e] += u4.x * v4.x + u4.y * v4.y + u4.z * v4.z + u4.w * v4.w;
        }
    }
    const float4 m0 = *reinterpret_cast<const float4*>(mask + (size_t)l * S + sb);
    const float4 m1 = *reinterpret_cast<const float4*>(mask + (size_t)l * S + sb + 4);
    bf16x8 pk;
    pk[0] = (__bf16)(acc[0] + m0.x); pk[1] = (__bf16)(acc[1] + m0.y);
    pk[2] = (__bf16)(acc[2] + m0.z); pk[3] = (__bf16)(acc[3] + m0.w);
    pk[4] = (__bf16)(acc[4] + m1.x); pk[5] = (__bf16)(acc[5] + m1.y);
    pk[6] = (__bf16)(acc[6] + m1.z); pk[7] = (__bf16)(acc[7] + m1.w);
    reinterpret_cast<bf16x8*>(Ap)[(size_t)(mtA * 16 + ks) * 64 + lane] = pk;
}

// K2: per-block B-panel build (raw K/V -> LDS features -> bf16 fragments)
// + MFMA + fused epilogue. grid 512, XCD-swizzled (nh in {xcd, xcd+8}).
__global__ __launch_bounds__(256) void aft_main_kernel(
    const float* __restrict__ keys, const float* __restrict__ values,
    const float* __restrict__ klen, const __bf16* __restrict__ Ap,
    const float* __restrict__ queries, float* __restrict__ out)
{
    __shared__ float  planes[2 * 16 * PADS];   // N plane then D plane (34 KB)
    __shared__ bf16x8 frag[2048];              // [0..1023]=N units, [1024..2047]=D
    __shared__ float  svred[16][65];
    __shared__ float  svl[16];

    const int b = blockIdx.x;
    const int xcd = b & 7;
    const int i = b >> 3;                   // 0..63
    const int nh = xcd + ((i >> 5) << 3);   // {xcd, xcd+8}
    const int rem = i & 31;
    const int mt = rem >> 2;
    const int dt = rem & 3;
    const int n = nh >> 3, h = nh & 7;

    const int t = threadIdx.x;
    const int wv = t >> 6;
    const int lane = t & 63;
    const int r = lane & 15;
    const int kg = lane >> 4;

    // A strip prefetch: 16 x 1KB coalesced wave-loads, in flight during staging
    const bf16x8* A8 = reinterpret_cast<const bf16x8*>(Ap)
                       + (size_t)(mt * 4 + wv) * 1024 + lane;
    bf16x8 a[16];
    #pragma unroll
    for (int ks = 0; ks < 16; ++ks) a[ks] = A8[(size_t)ks * 64];

    // staging geometry: thread owns d-quad c4 and s-rows (shi*16+sidx) + rg*64
    const int c4   = ((t >> 4) & 3) << 2;
    const int shi  = t >> 6;
    const int sidx = t & 15;
    const int srow = shi * 16 + sidx;       // 0..63
    const size_t kvbase = ((size_t)n * S * H + h) * D + dt * 16 + c4;
    const float* kb = keys + kvbase;
    const float* vb = values + kvbase;
    const float* klb = klen + (size_t)n * S;

    float sva[4] = {0.f, 0.f, 0.f, 0.f};

    #pragma unroll
    for (int half = 0; half < 2; ++half) {
        // ---- features into f32 planes (coalesced 64B-row loads) ----
        #pragma unroll
        for (int rg = 0; rg < 4; ++rg) {
            const int sl = rg * 64 + srow;          // 0..255 local
            const int s = half * 256 + sl;
            const float kl = klb[s];
            const f32x4 K4 = *reinterpret_cast<const f32x4*>(kb + (size_t)s * (H * D));
            const f32x4 V4 = *reinterpret_cast<const f32x4*>(vb + (size_t)s * (H * D));
            #pragma unroll
            for (int j = 0; j < 4; ++j) {
                const float kj = K4[j] + kl;
                planes[(c4 + j) * PADS + sl]        = kj * V4[j];
                planes[NOFF + (c4 + j) * PADS + sl] = kj;
                sva[j] += V4[j];
            }
        }
        __syncthreads();
        // ---- transpose-read -> bf16x8 fragment units (contiguous writes) ----
        #pragma unroll
        for (int m = 0; m < 4; ++m) {
            const int uid = ((m & 1) << 8) + t;     // 0..511
            const int ru  = uid & 15;
            const int kgu = (uid >> 4) & 3;
            const int ksl = uid >> 6;               // 0..7
            const int po = (m < 2 ? 0 : NOFF) + ru * PADS + ksl * 32 + kgu * 8;
            bf16x8 pk;
            #pragma unroll
            for (int e = 0; e < 8; ++e) pk[e] = (__bf16)planes[po + e];
            frag[(m < 2 ? 0 : 1024) + (half * 8 + ksl) * 64 + kgu * 16 + ru] = pk;
        }
        __syncthreads();
    }

    // ---- SV reduction (sum_s V per d-col) ----
    #pragma unroll
    for (int j = 0; j < 4; ++j) svred[c4 + j][srow] = sva[j];
    // early epilogue loads while reducing
    const int dcol = dt * 16 + r;
    const int l0 = (mt << 6) + (wv << 4);
    float qv[4];
    size_t qidx[4];
    #pragma unroll
    for (int rr = 0; rr < 4; ++rr) {
        const int l = l0 + (kg << 2) + rr;
        qidx[rr] = (((size_t)n * L + l) * H + h) * D + dcol;
        qv[rr] = queries[qidx[rr]];
    }
    __syncthreads();
    if (t < 16) {
        float sum = 0.f;
        #pragma unroll
        for (int j = 0; j < 64; ++j) sum += svred[t][j];
        svl[t] = sum;
    }
    __syncthreads();

    // ---- MFMA: pure register+LDS ----
    f32x4 accn = {0.f, 0.f, 0.f, 0.f};
    f32x4 accd = {0.f, 0.f, 0.f, 0.f};
    #pragma unroll
    for (int ks = 0; ks < 16; ++ks) {
        const bf16x8 bn = frag[ks * 64 + lane];
        const bf16x8 bd = frag[1024 + ks * 64 + lane];
        accn = mfma16(a[ks], bn, accn);
        accd = mfma16(a[ks], bd, accd);
    }

    const float sv = svl[r];
    #pragma unroll
    for (int rr = 0; rr < 4; ++rr) {
        const float sig =
            __builtin_amdgcn_rcpf(1.0f + __builtin_amdgcn_exp2f(-qv[rr] * LOG2E));
        const float numv = sv + accn[rr];
        const float denv = 512.0f + accd[rr];
        out[qidx[rr]] = sig * numv * __builtin_amdgcn_rcpf(denv);
    }
}
} // namespace

extern "C" void kernel_launch(void* const* d_in, const int* in_sizes, int n_in,
                              void* d_out, int out_size, void* d_ws, size_t ws_size,
                              hipStream_t stream)
{
    const float* queries = (const float*)d_in[0];
    const float* keys    = (const float*)d_in[1];
    const float* values  = (const float*)d_in[2];
    const float* mask    = (const float*)d_in[3];
    const float* klen    = (const float*)d_in[4];
    const float* u       = (const float*)d_in[5];
    const float* v       = (const float*)d_in[6];
    float* out = (float*)d_out;

    __bf16* Ap = (__bf16*)d_ws;   // 512 KiB

    aft_a_kernel<<<dim3(128), dim3(256), 0, stream>>>(u, v, mask, Ap);
    aft_main_kernel<<<dim3(512), dim3(256), 0, stream>>>(
        keys, values, klen, Ap, queries, out);
}

// Round 12
// 16.059 us; speedup vs baseline: 1.3156x; 1.3156x over previous
//
#include <hip/hip_runtime.h>
#include <math.h>

namespace {
constexpr int L = 512, S = 512, H = 8, D = 64, K64 = 64;
constexpr float LOG2E = 1.4426950408889634f;

typedef __bf16 bf16x8 __attribute__((ext_vector_type(8)));
typedef __bf16 bf16x2 __attribute__((ext_vector_type(2)));
typedef float  f32x4  __attribute__((ext_vector_type(4)));

// ws layout (bytes):
//   Ap : [32 mt][16 ks][4 kg][16 r] bf16x8        = 512 KiB @ 0
//        A[l][k]: l = mt*16+r, k = ks*32+kg*8+e; A = bf16(u@v^T + mask)
//   Bp : [16 nh][8 ct][16 ks][4 kg][16 r] bf16x8  = 2 MiB   @ 1 MiB
//        B^T[col][k]: col = ct*16+r; col<64 -> (K+kl)*V(d=col), col>=64 -> K+kl
//   SVp: [16 nh][64 d][16 sc] f32                 = 64 KiB  @ 3 MiB
constexpr size_t ABUF_OFF = 0;
constexpr size_t BBUF_OFF = 1u << 20;
constexpr size_t SVP_OFF  = 3u << 20;

__device__ inline f32x4 mfma16(bf16x8 a, bf16x8 b, f32x4 c) {
    return __builtin_amdgcn_mfma_f32_16x16x32_bf16(a, b, c, 0, 0, 0);
}

// Prep kernel: 512 blocks x 256 threads.
//   blocks 0..255  : A-role — w = u.v + mask (32x32 tile, 2x2/thread), bf16 pack
//                    (R9's proven fastest A variant, unchanged)
//   blocks 256..511: B-role — float4 K/V loads (1KB/wave-instr) -> LDS planes
//                    {(K+kl)*V, K+kl}; SV accumulated in-register during load;
//                    transpose-out to packed Bp identical to R9.
//                    Block for nh lands on XCD nh%8 (bid%8==nh%8), matching
//                    the gemm swizzle -> Bp/SVp L2-resident for the reader.
__global__ __launch_bounds__(256) void aft_prep_kernel(
    const float* __restrict__ u, const float* __restrict__ v,
    const float* __restrict__ mask, const float* __restrict__ keys,
    const float* __restrict__ values, const float* __restrict__ klen,
    __bf16* __restrict__ Ap, __bf16* __restrict__ Bp, float* __restrict__ SVp)
{
    __shared__ float lds[128 * 33];    // B-role transpose planes (16896 B)
    __shared__ float svred[64][17];    // per-(d, sr) V partials

    const int bid = blockIdx.x;
    const int t = threadIdx.x;

    if (bid < 256) {
        // ---------------- A role (R9-identical) ----------------
        const int l0 = (bid >> 4) << 5;
        const int s0 = (bid & 15) << 5;
        const int lb = l0 + ((t >> 4) << 1);
        const int sb = s0 + ((t & 15) << 1);

        float acc[2][2] = {};
        #pragma unroll
        for (int k = 0; k < K64; k += 4) {
            float4 uu[2], vv[2];
            #pragma unroll
            for (int i = 0; i < 2; ++i)
                uu[i] = *reinterpret_cast<const float4*>(u + (size_t)(lb + i) * K64 + k);
            #pragma unroll
            for (int j = 0; j < 2; ++j)
                vv[j] = *reinterpret_cast<const float4*>(v + (size_t)(sb + j) * K64 + k);
            #pragma unroll
            for (int i = 0; i < 2; ++i)
                #pragma unroll
                for (int j = 0; j < 2; ++j)
                    acc[i][j] += uu[i].x * vv[j].x + uu[i].y * vv[j].y
                               + uu[i].z * vv[j].z + uu[i].w * vv[j].w;
        }
        #pragma unroll
        for (int i = 0; i < 2; ++i) {
            const int l = lb + i;
            const float2 mk = *reinterpret_cast<const float2*>(mask + (size_t)l * S + sb);
            const float w0 = acc[i][0] + mk.x;
            const float w1 = acc[i][1] + mk.y;
            const size_t unit = (((size_t)(l >> 4) * 16 + (sb >> 5)) * 4
                                 + ((sb >> 3) & 3)) * 16 + (l & 15);
            bf16x2 pk; pk[0] = (__bf16)w0; pk[1] = (__bf16)w1;
            *reinterpret_cast<bf16x2*>(Ap + unit * 8 + (sb & 7)) = pk;
        }
    } else {
        // ---------------- B role (float4 loads) ----------------
        const int bb = bid - 256;              // bb%8 == nh%8
        const int nh = bb & 15;
        const int sc = bb >> 4;
        const int n = nh >> 3, h = nh & 7;
        const int s0 = sc << 5;

        const int c4 = (t & 15) << 2;          // d base 0..60
        const int sr = t >> 4;                 // 0..15

        float sva[4] = {0.f, 0.f, 0.f, 0.f};
        #pragma unroll
        for (int rg = 0; rg < 2; ++rg) {
            const int sloc = sr + (rg << 4);   // 0..31
            const int s = s0 + sloc;
            const float kl = klen[n * S + s];
            const size_t gi = (((size_t)n * S + s) * H + h) * D + c4;
            const f32x4 K4 = *reinterpret_cast<const f32x4*>(keys + gi);
            const f32x4 V4 = *reinterpret_cast<const f32x4*>(values + gi);
            #pragma unroll
            for (int j = 0; j < 4; ++j) {
                const float kj = K4[j] + kl;
                lds[(c4 + j) * 33 + sloc]        = kj * V4[j];
                lds[(64 + c4 + j) * 33 + sloc]   = kj;
                sva[j] += V4[j];
            }
        }
        #pragma unroll
        for (int j = 0; j < 4; ++j) svred[c4 + j][sr] = sva[j];
        __syncthreads();

        if (t < 64) {
            float sum = 0.f;
            #pragma unroll
            for (int j = 0; j < 16; ++j) sum += svred[t][j];
            SVp[((size_t)nh * 64 + t) * 16 + sc] = sum;
        }

        const int col = t & 127;
        const int hf = t >> 7;                 // s-half: j = hf*16 + j2
        __bf16 tmp[16];
        #pragma unroll
        for (int j2 = 0; j2 < 16; ++j2)
            tmp[j2] = (__bf16)lds[col * 33 + (hf << 4) + j2];
        __bf16* dst = Bp + ((((size_t)nh * 8 + (col >> 4)) * 16 + sc) * 4
                            + (hf << 1)) * 128 + (size_t)(col & 15) * 8;
        *reinterpret_cast<bf16x8*>(dst)       = *reinterpret_cast<bf16x8*>(&tmp[0]);
        *reinterpret_cast<bf16x8*>(dst + 128) = *reinterpret_cast<bf16x8*>(&tmp[8]);
    }
}

// GEMM: C = A(512x512) x B_nh(512x128); fused epilogue
//   out = sigmoid(q) * (SV + C_num) / (512 + C_den)
// grid 512, XCD-swizzled (nh in {xcd, xcd+8}); 256 threads = 4 waves.
// A strip fully prefetched to registers; N/D panels staged to LDS; queries
// and SVp prefetched before the barrier so epilogue latency hides under
// staging. Inner loop is pure register+LDS MFMA.
__global__ __launch_bounds__(256) void aft_gemm_kernel(
    const __bf16* __restrict__ Ap, const __bf16* __restrict__ Bp,
    const float* __restrict__ SVp, const float* __restrict__ queries,
    float* __restrict__ out)
{
    __shared__ bf16x8 ldsB[2048];   // 32 KiB: [0..1023]=num panel, [1024..2047]=den

    const int b = blockIdx.x;
    const int xcd = b & 7;
    const int i = b >> 3;                   // 0..63
    const int nh = xcd + ((i >> 5) << 3);   // {xcd, xcd+8}
    const int rem = i & 31;
    const int mt = rem >> 2;
    const int dt = rem & 3;
    const int n = nh >> 3, h = nh & 7;

    const int t = threadIdx.x;
    const int wv = t >> 6;
    const int lane = t & 63;
    const int r = lane & 15;
    const int kg = lane >> 4;

    // stage B panels (contiguous 16 KB each in packed layout) via registers
    const bf16x8* Nsrc = reinterpret_cast<const bf16x8*>(Bp)
                         + (size_t)nh * 8192 + (size_t)dt * 1024;
    const bf16x8* Dsrc = Nsrc + 4 * 1024;
    bf16x8 st[8];
    #pragma unroll
    for (int c = 0; c < 4; ++c) st[c]     = Nsrc[c * 256 + t];
    #pragma unroll
    for (int c = 0; c < 4; ++c) st[4 + c] = Dsrc[c * 256 + t];

    // prefetch entire A strip for this wave (16 x 1KB wave-loads, all in flight)
    const bf16x8* A8 = reinterpret_cast<const bf16x8*>(Ap)
                       + (size_t)(mt * 4 + wv) * 1024 + lane;
    bf16x8 a[16];
    #pragma unroll
    for (int ks = 0; ks < 16; ++ks) a[ks] = A8[(size_t)ks * 64];

    // early epilogue loads: SV partials + queries (hide under staging/barrier)
    const int dcol = (dt << 4) + r;
    const float* svp = SVp + ((size_t)nh * 64 + dcol) * 16;
    const f32x4 s0 = *reinterpret_cast<const f32x4*>(svp);
    const f32x4 s1 = *reinterpret_cast<const f32x4*>(svp + 4);
    const f32x4 s2 = *reinterpret_cast<const f32x4*>(svp + 8);
    const f32x4 s3 = *reinterpret_cast<const f32x4*>(svp + 12);
    const int l0 = (mt << 6) + (wv << 4);
    float qv[4];
    size_t qidx[4];
    #pragma unroll
    for (int rr = 0; rr < 4; ++rr) {
        const int l = l0 + (kg << 2) + rr;
        qidx[rr] = (((size_t)n * L + l) * H + h) * D + dcol;
        qv[rr] = queries[qidx[rr]];
    }

    #pragma unroll
    for (int c = 0; c < 4; ++c) ldsB[c * 256 + t]        = st[c];
    #pragma unroll
    for (int c = 0; c < 4; ++c) ldsB[1024 + c * 256 + t] = st[4 + c];
    __syncthreads();

    f32x4 accn = {0.f, 0.f, 0.f, 0.f};
    f32x4 accd = {0.f, 0.f, 0.f, 0.f};

    #pragma unroll
    for (int ks = 0; ks < 16; ++ks) {
        const bf16x8 bn = ldsB[ks * 64 + lane];
        const bf16x8 bd = ldsB[1024 + ks * 64 + lane];
        accn = mfma16(a[ks], bn, accn);
        accd = mfma16(a[ks], bd, accd);
    }

    const float sv = ((s0[0] + s0[1]) + (s0[2] + s0[3]))
                   + ((s1[0] + s1[1]) + (s1[2] + s1[3]))
                   + ((s2[0] + s2[1]) + (s2[2] + s2[3]))
                   + ((s3[0] + s3[1]) + (s3[2] + s3[3]));

    #pragma unroll
    for (int rr = 0; rr < 4; ++rr) {
        const float sig =
            __builtin_amdgcn_rcpf(1.0f + __builtin_amdgcn_exp2f(-qv[rr] * LOG2E));
        const float numv = sv + accn[rr];
        const float denv = 512.0f + accd[rr];
        out[qidx[rr]] = sig * numv * __builtin_amdgcn_rcpf(denv);
    }
}
} // namespace

extern "C" void kernel_launch(void* const* d_in, const int* in_sizes, int n_in,
                              void* d_out, int out_size, void* d_ws, size_t ws_size,
                              hipStream_t stream)
{
    const float* queries = (const float*)d_in[0];
    const float* keys    = (const float*)d_in[1];
    const float* values  = (const float*)d_in[2];
    const float* mask    = (const float*)d_in[3];
    const float* klen    = (const float*)d_in[4];
    const float* u       = (const float*)d_in[5];
    const float* v       = (const float*)d_in[6];
    float* out = (float*)d_out;

    char* ws = (char*)d_ws;
    __bf16* Ap = (__bf16*)(ws + ABUF_OFF);
    __bf16* Bp = (__bf16*)(ws + BBUF_OFF);
    float*  SVp = (float*)(ws + SVP_OFF);

    aft_prep_kernel<<<dim3(512), dim3(256), 0, stream>>>(
        u, v, mask, keys, values, klen, Ap, Bp, SVp);
    aft_gemm_kernel<<<dim3(512), dim3(256), 0, stream>>>(
        Ap, Bp, SVp, queries, out);
}